// Round 1
// baseline (607.905 us; speedup 1.0000x reference)
//
#include <hip/hip_runtime.h>

// PluginEmbedding: CSR sparse-embedding lookup + per-row sum combine.
// In this instance row_offsets = arange(NNZ+1) -> exactly 1 nnz/row, i.e. a
// pure gather of 512 B rows from a 512 MB table. We still implement the
// general CSR sum (start..end loop) for robustness; it degenerates to one
// iteration.
//
// Layout: 32 lanes per output row; lane c handles float4 #c of the 128-float
// row. Gather read: 32 lanes x 16 B = 512 B contiguous per row (4 full cache
// lines, zero over-fetch). Write: fully coalesced float4.

#define ROW_F4 32  // 128 floats = 32 float4 per row

__global__ __launch_bounds__(256) void plugin_embedding_gather(
    const float4* __restrict__ table,
    const int*    __restrict__ row_offsets,
    const int*    __restrict__ vals,
    float4*       __restrict__ out,
    int n_rows)
{
    int t   = blockIdx.x * blockDim.x + threadIdx.x;
    int row = t >> 5;     // 32 threads per row
    int col = t & 31;
    if (row >= n_rows) return;

    int start = row_offsets[row];
    int end   = row_offsets[row + 1];

    float4 acc = make_float4(0.f, 0.f, 0.f, 0.f);
    for (int j = start; j < end; ++j) {
        int idx = vals[j];
        float4 v = table[(size_t)idx * ROW_F4 + col];
        acc.x += v.x; acc.y += v.y; acc.z += v.z; acc.w += v.w;
    }
    out[(size_t)row * ROW_F4 + col] = acc;
}

extern "C" void kernel_launch(void* const* d_in, const int* in_sizes, int n_in,
                              void* d_out, int out_size, void* d_ws, size_t ws_size,
                              hipStream_t stream) {
    const float4* table       = (const float4*)d_in[0];
    const int*    row_offsets = (const int*)d_in[1];
    const int*    vals        = (const int*)d_in[2];
    float4*       out         = (float4*)d_out;

    // out_size = n_rows * 128 floats
    int n_rows = out_size / 128;

    long long total_threads = (long long)n_rows * ROW_F4;
    int block = 256;
    int grid  = (int)((total_threads + block - 1) / block);

    plugin_embedding_gather<<<grid, block, 0, stream>>>(
        table, row_offsets, vals, out, n_rows);
}